// Round 2
// baseline (112.070 us; speedup 1.0000x reference)
//
#include <hip/hip_runtime.h>
#include <hip/hip_bf16.h>
#include <stdint.h>

typedef __attribute__((ext_vector_type(4))) float f32x4;
typedef __attribute__((ext_vector_type(2))) float f32x2;
typedef __attribute__((ext_vector_type(8))) short short8;
typedef __attribute__((ext_vector_type(4))) int int4v;

#define IN_F   8192
#define OUT_F  8192
#define MROWS  256
#define BN     128
#define BK     64
#define NGRP   128   // IN_F / 64

// Static device scratch — no dependence on d_ws/ws_size.
__device__ unsigned short g_xb[MROWS * IN_F];        // 4 MB bf16 x, tiled+swizzled
__device__ float          g_t[MROWS * 16];           // 16 KB LoRA intermediate
__device__ float          g_part[4 * MROWS * OUT_F]; // 32 MB split-K partials

// NF4 levels: Phi^{-1}((i+0.5)/16) / Phi^{-1}(15.5/16)
__device__ __constant__ float NF4_LVL[16] = {
  -1.0f,        -0.70756721f, -0.54221982f, -0.41681853f,
  -0.31090474f, -0.21594601f, -0.12734085f, -0.04209530f,
   0.04209530f,  0.12734085f,  0.21594601f,  0.31090474f,
   0.41681853f,  0.54221982f,  0.70756721f,  1.0f };

static __device__ inline uint32_t pkbf(float a, float b) {
  __bf16 ha = (__bf16)a, hb = (__bf16)b;
  return (uint32_t)__builtin_bit_cast(unsigned short, ha)
       | ((uint32_t)__builtin_bit_cast(unsigned short, hb) << 16);
}

// ---- k0: x fp32 -> bf16, tiled [ktile][row][chunk ^ (row&7)][8]
__global__ __launch_bounds__(256) void k_convert(const float* __restrict__ x) {
  int cid = blockIdx.x * 256 + threadIdx.x;   // 128*256*8 = 262144 chunks
  int kt = cid >> 11;
  int r  = (cid >> 3) & 255;
  int c  = cid & 7;
  const float* src = x + (size_t)r * IN_F + kt * 64 + c * 8;
  f32x4 v0 = *(const f32x4*)src;
  f32x4 v1 = *(const f32x4*)(src + 4);
  int4v ov;
  ov[0] = (int)pkbf(v0.x, v0.y); ov[1] = (int)pkbf(v0.z, v0.w);
  ov[2] = (int)pkbf(v1.x, v1.y); ov[3] = (int)pkbf(v1.z, v1.w);
  *(int4v*)(g_xb + (size_t)kt * 16384 + r * 64 + ((c ^ (r & 7)) << 3)) = ov;
}

// ---- k1: t = SCALING * x @ lora_A^T   (256 x 16)
__global__ __launch_bounds__(256) void k_xa(const float* __restrict__ x,
                                            const float* __restrict__ lora_A) {
  int m = blockIdx.x, tid = threadIdx.x;
  float acc[16];
#pragma unroll
  for (int r = 0; r < 16; ++r) acc[r] = 0.f;
  const float* xr = x + (size_t)m * IN_F;
  for (int it = 0; it < 8; ++it) {
    int k = (tid + it * 256) * 4;
    f32x4 xv = *(const f32x4*)(xr + k);
#pragma unroll
    for (int r = 0; r < 16; ++r) {
      f32x4 av = *(const f32x4*)(lora_A + (size_t)r * IN_F + k);
      acc[r] += xv.x * av.x + xv.y * av.y + xv.z * av.z + xv.w * av.w;
    }
  }
#pragma unroll
  for (int r = 0; r < 16; ++r) {
    float v = acc[r];
#pragma unroll
    for (int off = 32; off; off >>= 1) v += __shfl_xor(v, off, 64);
    acc[r] = v;
  }
  __shared__ float sm[4][16];
  int lane = tid & 63, wave = tid >> 6;
  if (lane == 0) {
#pragma unroll
    for (int r = 0; r < 16; ++r) sm[wave][r] = acc[r];
  }
  __syncthreads();
  if (tid < 16)
    g_t[m * 16 + tid] = 2.0f * (sm[0][tid] + sm[1][tid] + sm[2][tid] + sm[3][tid]);
}

// ---- k2: out = t @ lora_B^T (pre-store LoRA term; k_reduce adds GEMM on top)
__global__ __launch_bounds__(256) void k_lora(const float* __restrict__ lora_B,
                                              float* __restrict__ out) {
  int bid = blockIdx.x;
  int m = bid >> 5;
  int n = ((bid & 31) << 8) + threadIdx.x;
  const float* tr = g_t + m * 16;
  f32x4 t0 = *(const f32x4*)tr,       t1 = *(const f32x4*)(tr + 4);
  f32x4 t2 = *(const f32x4*)(tr + 8), t3 = *(const f32x4*)(tr + 12);
  const float* br = lora_B + (size_t)n * 16;
  f32x4 b0 = *(const f32x4*)br,       b1 = *(const f32x4*)(br + 4);
  f32x4 b2 = *(const f32x4*)(br + 8), b3 = *(const f32x4*)(br + 12);
  float v = t0.x*b0.x + t0.y*b0.y + t0.z*b0.z + t0.w*b0.w
          + t1.x*b1.x + t1.y*b1.y + t1.z*b1.z + t1.w*b1.w
          + t2.x*b2.x + t2.y*b2.y + t2.z*b2.z + t2.w*b2.w
          + t3.x*b3.x + t3.y*b3.y + t3.z*b3.z + t3.w*b3.w;
  out[(size_t)m * OUT_F + n] = v;
}

// ---- k3: main GEMM. BM=256(all M) x BN=128, BK=64, split-K=4. NF4->bf16 dequant in LDS.
__global__ __launch_bounds__(512, 2) void k_gemm(
    const int* __restrict__ qw, const float* __restrict__ scales)
{
  __shared__ unsigned short Al[MROWS * BK];  // 32 KB
  __shared__ unsigned short Bl[BN * BK];     // 16 KB
  __shared__ f32x2 lut[256];                 // 2 KB

  int tid = threadIdx.x;
  int lane = tid & 63, wave = tid >> 6;

  if (tid < 256) {
    f32x2 e; e.x = NF4_LVL[tid >> 4]; e.y = NF4_LVL[tid & 15];
    lut[tid] = e;
  }

  // XCD-aware bijective swizzle over 256 blocks
  int flat = blockIdx.y * 64 + blockIdx.x;
  int wg = (flat & 7) * 32 + (flat >> 3);
  int bx = wg & 63, bz = wg >> 6;   // bx: N-tile, bz: k-slice

  int n0 = bx * BN;
  int ktg0 = bz * 32;               // 32 k-tiles (of 64) per slice

  f32x4 acc[4][4];
#pragma unroll
  for (int i = 0; i < 4; ++i)
#pragma unroll
    for (int j = 0; j < 4; ++j) acc[i][j] = (f32x4){0.f, 0.f, 0.f, 0.f};

  int wr = wave >> 1, wc = wave & 1;
  int wm = wr * 64, wn = wc * 64;

  __syncthreads();  // lut ready

  for (int kt = 0; kt < 32; ++kt) {
    int ktg = ktg0 + kt;
    if (kt) __syncthreads();

    // stage A: 4 x global_load_lds (16B); g_xb tile is an exact linear image of Al
    {
      const char* src = (const char*)g_xb + (size_t)ktg * 32768 + tid * 16;
      char* dst = (char*)Al + tid * 16;
#pragma unroll
      for (int j = 0; j < 4; ++j) {
        __builtin_amdgcn_global_load_lds(
            (const __attribute__((address_space(1))) void*)(src + j * 8192),
            (__attribute__((address_space(3))) void*)(dst + j * 8192), 16, 0, 0);
      }
    }

    // stage B: dequant 2 chunks (8 weights each) per thread
#pragma unroll
    for (int t2 = 0; t2 < 2; ++t2) {
      int u = tid + t2 * 512;
      int n = u >> 3, c = u & 7;
      int grow = n0 + n;
      float s = scales[(size_t)grow * NGRP + ktg];
      int4v q = *(const int4v*)(qw + (size_t)grow * (IN_F / 2) + ktg * 32 + c * 4);
      int4v ov;
#pragma unroll
      for (int e = 0; e < 4; ++e) {
        f32x2 lv = lut[q[e] & 255];
        ov[e] = (int)pkbf(lv.x * s, lv.y * s);
      }
      *(int4v*)((char*)Bl + n * 128 + ((c ^ (n & 7)) << 4)) = ov;
    }
    __syncthreads();

    // compute: 2 x (8 ds_read_b128 + 16 MFMA)
#pragma unroll
    for (int kk = 0; kk < 2; ++kk) {
      short8 af[4], bfv[4];
#pragma unroll
      for (int mi = 0; mi < 4; ++mi) {
        int r = wm + mi * 16 + (lane & 15);
        int cch = (kk * 4 + (lane >> 4)) ^ (r & 7);
        af[mi] = *(const short8*)((const char*)Al + r * 128 + cch * 16);
      }
#pragma unroll
      for (int ni = 0; ni < 4; ++ni) {
        int n = wn + ni * 16 + (lane & 15);
        int cch = (kk * 4 + (lane >> 4)) ^ (n & 7);
        bfv[ni] = *(const short8*)((const char*)Bl + n * 128 + cch * 16);
      }
#pragma unroll
      for (int mi = 0; mi < 4; ++mi)
#pragma unroll
        for (int ni = 0; ni < 4; ++ni)
          acc[mi][ni] = __builtin_amdgcn_mfma_f32_16x16x32_bf16(
              af[mi], bfv[ni], acc[mi][ni], 0, 0, 0);
    }
  }

  // epilogue -> per-slice partial buffer. D layout: col=lane&15, row=(lane>>4)*4+reg
  float* op = g_part + (size_t)bz * MROWS * OUT_F;
#pragma unroll
  for (int mi = 0; mi < 4; ++mi) {
#pragma unroll
    for (int ni = 0; ni < 4; ++ni) {
      int m = wm + mi * 16 + (lane >> 4) * 4;
      int nn = n0 + wn + ni * 16 + (lane & 15);
#pragma unroll
      for (int j = 0; j < 4; ++j)
        op[(size_t)(m + j) * OUT_F + nn] = acc[mi][ni][j];
    }
  }
}

// ---- k4: out += sum of 4 split-K partials
__global__ __launch_bounds__(256) void k_reduce(float* __restrict__ out) {
  size_t i = ((size_t)blockIdx.x * 256 + threadIdx.x) * 4;
  f32x4 v = *(f32x4*)(out + i);
#pragma unroll
  for (int s = 0; s < 4; ++s)
    v += *(const f32x4*)(g_part + (size_t)s * MROWS * OUT_F + i);
  *(f32x4*)(out + i) = v;
}

extern "C" void kernel_launch(void* const* d_in, const int* in_sizes, int n_in,
                              void* d_out, int out_size, void* d_ws, size_t ws_size,
                              hipStream_t stream) {
  const float* x  = (const float*)d_in[0];
  const int*   qw = (const int*)d_in[1];
  const float* sc = (const float*)d_in[2];
  const float* lA = (const float*)d_in[3];
  const float* lB = (const float*)d_in[4];
  float* out = (float*)d_out;

  k_convert<<<1024, 256, 0, stream>>>(x);
  k_xa<<<256, 256, 0, stream>>>(x, lA);
  k_lora<<<8192, 256, 0, stream>>>(lB, out);
  k_gemm<<<dim3(64, 4), 512, 0, stream>>>(qw, sc);
  k_reduce<<<2048, 256, 0, stream>>>(out);
}

// Round 3
// 107.505 us; speedup vs baseline: 1.0425x; 1.0425x over previous
//
#include <hip/hip_runtime.h>
#include <hip/hip_bf16.h>
#include <stdint.h>

typedef __attribute__((ext_vector_type(4))) float f32x4;
typedef __attribute__((ext_vector_type(8))) short short8;
typedef __attribute__((ext_vector_type(4))) int int4v;

#define IN_F   8192
#define OUT_F  8192
#define MROWS  256
#define BN     128
#define BK     64
#define NGRP   128   // IN_F / 64

// Static device scratch — no dependence on d_ws/ws_size.
__device__ unsigned short g_xb[MROWS * IN_F];        // 4 MB bf16 x, tiled+swizzled
__device__ float          g_t[MROWS * 16];           // LoRA intermediate (pre-scaled by 2)
__device__ float          g_part[4 * MROWS * OUT_F]; // 32 MB split-K partials

// NF4 levels: Phi^{-1}((i+0.5)/16) / Phi^{-1}(15.5/16)
__device__ __constant__ float NF4_LVL[16] = {
  -1.0f,        -0.70756721f, -0.54221982f, -0.41681853f,
  -0.31090474f, -0.21594601f, -0.12734085f, -0.04209530f,
   0.04209530f,  0.12734085f,  0.21594601f,  0.31090474f,
   0.41681853f,  0.54221982f,  0.70756721f,  1.0f };

static __device__ inline uint32_t pkbf(float a, float b) {
  __bf16 ha = (__bf16)a, hb = (__bf16)b;
  return (uint32_t)__builtin_bit_cast(unsigned short, ha)
       | ((uint32_t)__builtin_bit_cast(unsigned short, hb) << 16);
}

// ---- k0: x fp32 -> bf16, tiled [ktile][row][chunk ^ (row&7)][8]
__global__ __launch_bounds__(256) void k_convert(const float* __restrict__ x) {
  int cid = blockIdx.x * 256 + threadIdx.x;   // 262144 chunks
  int kt = cid >> 11;
  int r  = (cid >> 3) & 255;
  int c  = cid & 7;
  const float* src = x + (size_t)r * IN_F + kt * 64 + c * 8;
  f32x4 v0 = *(const f32x4*)src;
  f32x4 v1 = *(const f32x4*)(src + 4);
  int4v ov;
  ov[0] = (int)pkbf(v0.x, v0.y); ov[1] = (int)pkbf(v0.z, v0.w);
  ov[2] = (int)pkbf(v1.x, v1.y); ov[3] = (int)pkbf(v1.z, v1.w);
  *(int4v*)(g_xb + (size_t)kt * 16384 + r * 64 + ((c ^ (r & 7)) << 3)) = ov;
}

// ---- k1: g_t = 2 * x @ lora_A^T   (256 x 16)
__global__ __launch_bounds__(256) void k_xa(const float* __restrict__ x,
                                            const float* __restrict__ lora_A) {
  int m = blockIdx.x, tid = threadIdx.x;
  float acc[16];
#pragma unroll
  for (int r = 0; r < 16; ++r) acc[r] = 0.f;
  const float* xr = x + (size_t)m * IN_F;
  for (int it = 0; it < 8; ++it) {
    int k = (tid + it * 256) * 4;
    f32x4 xv = *(const f32x4*)(xr + k);
#pragma unroll
    for (int r = 0; r < 16; ++r) {
      f32x4 av = *(const f32x4*)(lora_A + (size_t)r * IN_F + k);
      acc[r] += xv.x * av.x + xv.y * av.y + xv.z * av.z + xv.w * av.w;
    }
  }
#pragma unroll
  for (int r = 0; r < 16; ++r) {
    float v = acc[r];
#pragma unroll
    for (int off = 32; off; off >>= 1) v += __shfl_xor(v, off, 64);
    acc[r] = v;
  }
  __shared__ float sm[4][16];
  int lane = tid & 63, wave = tid >> 6;
  if (lane == 0) {
#pragma unroll
    for (int r = 0; r < 16; ++r) sm[wave][r] = acc[r];
  }
  __syncthreads();
  if (tid < 16)
    g_t[m * 16 + tid] = 2.0f * (sm[0][tid] + sm[1][tid] + sm[2][tid] + sm[3][tid]);
}

// ---- k3: main GEMM. BM=256 x BN=128, BK=64, split-K=4. Double-buffered LDS,
//      1 raw barrier per k-tile, q prefetched one tile ahead into regs.
__global__ __launch_bounds__(512, 2) void k_gemm(
    const int* __restrict__ qw, const float* __restrict__ scales)
{
  __shared__ unsigned short Al[2][MROWS * BK];  // 2 x 32 KB
  __shared__ unsigned short Bl[2][BN * BK];     // 2 x 16 KB
  __shared__ float lut16[16];                   // 1 entry/bank -> conflict-free

  int tid = threadIdx.x;
  int lane = tid & 63, wave = tid >> 6;
  if (tid < 16) lut16[tid] = NF4_LVL[tid];
  __syncthreads();

  // XCD-aware bijective swizzle over 256 blocks
  int flat = blockIdx.y * 64 + blockIdx.x;
  int wg = (flat & 7) * 32 + (flat >> 3);
  int bx = wg & 63, bz = wg >> 6;   // bx: N-tile, bz: k-slice
  int n0 = bx * BN;
  int ktg0 = bz * 32;

  // stage-B per-thread geometry: 2 units (row n, 4-int chunk c)
  int n_0 = tid >> 3, c_0 = tid & 7;        // rows 0..63
  int n_1 = n_0 + 64;                       // rows 64..127
  const int* qr0 = qw + (size_t)(n0 + n_0) * (IN_F / 2) + c_0 * 4;
  const int* qr1 = qw + (size_t)(n0 + n_1) * (IN_F / 2) + c_0 * 4;
  const float* sr0 = scales + (size_t)(n0 + n_0) * NGRP;
  const float* sr1 = scales + (size_t)(n0 + n_1) * NGRP;
  int boff0 = n_0 * 128 + ((c_0 ^ (n_0 & 7)) << 4);
  int boff1 = boff0 + 64 * 128;

  f32x4 acc[4][4];
#pragma unroll
  for (int i = 0; i < 4; ++i)
#pragma unroll
    for (int j = 0; j < 4; ++j) acc[i][j] = (f32x4){0.f, 0.f, 0.f, 0.f};

  int wr = wave >> 1, wc = wave & 1;
  int wm = wr * 64, wn = wc * 64;

  auto stageA = [&](int buf, int kt) {
    const char* src = (const char*)g_xb + (size_t)kt * 32768 + tid * 16;
    char* dst = (char*)(&Al[buf][0]) + tid * 16;
#pragma unroll
    for (int j = 0; j < 4; ++j)
      __builtin_amdgcn_global_load_lds(
          (const __attribute__((address_space(1))) void*)(src + j * 8192),
          (__attribute__((address_space(3))) void*)(dst + j * 8192), 16, 0, 0);
  };

  auto dqst = [&](int buf, int4v q0, float s0, int4v q1, float s1) {
    char* Bb = (char*)(&Bl[buf][0]);
    int4v ov;
#pragma unroll
    for (int e = 0; e < 4; ++e) {
      float hi = lut16[(q0[e] >> 4) & 15];
      float lo = lut16[q0[e] & 15];
      ov[e] = (int)pkbf(hi * s0, lo * s0);
    }
    *(int4v*)(Bb + boff0) = ov;
#pragma unroll
    for (int e = 0; e < 4; ++e) {
      float hi = lut16[(q1[e] >> 4) & 15];
      float lo = lut16[q1[e] & 15];
      ov[e] = (int)pkbf(hi * s1, lo * s1);
    }
    *(int4v*)(Bb + boff1) = ov;
  };

  auto compute = [&](int buf) {
    const char* Ab = (const char*)(&Al[buf][0]);
    const char* Bb = (const char*)(&Bl[buf][0]);
#pragma unroll
    for (int kk = 0; kk < 2; ++kk) {
      short8 af[4], bfv[4];
#pragma unroll
      for (int mi = 0; mi < 4; ++mi) {
        int r = wm + mi * 16 + (lane & 15);
        int cch = (kk * 4 + (lane >> 4)) ^ (r & 7);
        af[mi] = *(const short8*)(Ab + r * 128 + cch * 16);
      }
#pragma unroll
      for (int ni = 0; ni < 4; ++ni) {
        int n = wn + ni * 16 + (lane & 15);
        int cch = (kk * 4 + (lane >> 4)) ^ (n & 7);
        bfv[ni] = *(const short8*)(Bb + n * 128 + cch * 16);
      }
      __builtin_amdgcn_s_setprio(1);
#pragma unroll
      for (int mi = 0; mi < 4; ++mi)
#pragma unroll
        for (int ni = 0; ni < 4; ++ni)
          acc[mi][ni] = __builtin_amdgcn_mfma_f32_16x16x32_bf16(
              af[mi], bfv[ni], acc[mi][ni], 0, 0, 0);
      __builtin_amdgcn_s_setprio(0);
    }
  };

  // ---- prologue: tile 0 into buf0, q[1] into regs
  int4v qa0 = *(const int4v*)(qr0 + ktg0 * 32);
  int4v qa1 = *(const int4v*)(qr1 + ktg0 * 32);
  float sa0 = sr0[ktg0], sa1 = sr1[ktg0];
  stageA(0, ktg0);
  int4v qb0 = *(const int4v*)(qr0 + (ktg0 + 1) * 32);
  int4v qb1 = *(const int4v*)(qr1 + (ktg0 + 1) * 32);
  float sb0 = sr0[ktg0 + 1], sb1 = sr1[ktg0 + 1];
  dqst(0, qa0, sa0, qa1, sa1);
  asm volatile("s_waitcnt vmcnt(0) lgkmcnt(0)" ::: "memory");
  __builtin_amdgcn_s_barrier();

  // ---- main loop: one barrier per k-tile
  for (int t = 0; t < 31; ++t) {
    int c = t & 1;
    int kn = ktg0 + ((t < 30) ? (t + 2) : 0);   // clamp: dummy reload at t=30
    int4v qn0 = *(const int4v*)(qr0 + kn * 32);
    int4v qn1 = *(const int4v*)(qr1 + kn * 32);
    float sn0 = sr0[kn], sn1 = sr1[kn];
    stageA(c ^ 1, ktg0 + t + 1);
    dqst(c ^ 1, qb0, sb0, qb1, sb1);
    compute(c);
    asm volatile("s_waitcnt vmcnt(0) lgkmcnt(0)" ::: "memory");
    __builtin_amdgcn_s_barrier();
    qb0 = qn0; qb1 = qn1; sb0 = sn0; sb1 = sn1;
  }
  compute(1);  // tile 31 sits in buf1

  // epilogue -> per-slice partial buffer. D layout: col=lane&15, row=(lane>>4)*4+reg
  float* op = g_part + (size_t)bz * MROWS * OUT_F;
#pragma unroll
  for (int mi = 0; mi < 4; ++mi) {
#pragma unroll
    for (int ni = 0; ni < 4; ++ni) {
      int m = wm + mi * 16 + (lane >> 4) * 4;
      int nn = n0 + wn + ni * 16 + (lane & 15);
#pragma unroll
      for (int j = 0; j < 4; ++j)
        op[(size_t)(m + j) * OUT_F + nn] = acc[mi][ni][j];
    }
  }
}

// ---- k4: out = sum of 4 split-K partials + LoRA (t @ lora_B^T), fused
__global__ __launch_bounds__(256) void k_reduce(const float* __restrict__ lora_B,
                                                float* __restrict__ out) {
  size_t i = ((size_t)blockIdx.x * 256 + threadIdx.x) * 4;
  int m = (int)(i >> 13);
  int n = (int)(i & 8191);
  f32x4 v = *(const f32x4*)(g_part + i);
  v += *(const f32x4*)(g_part + (size_t)1 * MROWS * OUT_F + i);
  v += *(const f32x4*)(g_part + (size_t)2 * MROWS * OUT_F + i);
  v += *(const f32x4*)(g_part + (size_t)3 * MROWS * OUT_F + i);
  const float* tr = g_t + m * 16;
  f32x4 t0 = *(const f32x4*)tr,       t1 = *(const f32x4*)(tr + 4);
  f32x4 t2 = *(const f32x4*)(tr + 8), t3 = *(const f32x4*)(tr + 12);
#pragma unroll
  for (int j = 0; j < 4; ++j) {
    const float* br = lora_B + (size_t)(n + j) * 16;
    f32x4 b0 = *(const f32x4*)br,       b1 = *(const f32x4*)(br + 4);
    f32x4 b2 = *(const f32x4*)(br + 8), b3 = *(const f32x4*)(br + 12);
    v[j] += t0.x*b0.x + t0.y*b0.y + t0.z*b0.z + t0.w*b0.w
          + t1.x*b1.x + t1.y*b1.y + t1.z*b1.z + t1.w*b1.w
          + t2.x*b2.x + t2.y*b2.y + t2.z*b2.z + t2.w*b2.w
          + t3.x*b3.x + t3.y*b3.y + t3.z*b3.z + t3.w*b3.w;
  }
  *(f32x4*)(out + i) = v;
}

extern "C" void kernel_launch(void* const* d_in, const int* in_sizes, int n_in,
                              void* d_out, int out_size, void* d_ws, size_t ws_size,
                              hipStream_t stream) {
  const float* x  = (const float*)d_in[0];
  const int*   qw = (const int*)d_in[1];
  const float* sc = (const float*)d_in[2];
  const float* lA = (const float*)d_in[3];
  const float* lB = (const float*)d_in[4];
  float* out = (float*)d_out;

  k_convert<<<1024, 256, 0, stream>>>(x);
  k_xa<<<256, 256, 0, stream>>>(x, lA);
  k_gemm<<<dim3(64, 4), 512, 0, stream>>>(qw, sc);
  k_reduce<<<2048, 256, 0, stream>>>(lB, out);
}

// Round 4
// 107.144 us; speedup vs baseline: 1.0460x; 1.0034x over previous
//
#include <hip/hip_runtime.h>
#include <hip/hip_bf16.h>
#include <stdint.h>

typedef __attribute__((ext_vector_type(4))) float f32x4;
typedef __attribute__((ext_vector_type(8))) short short8;
typedef __attribute__((ext_vector_type(4))) int int4v;

#define IN_F   8192
#define OUT_F  8192
#define MROWS  256
#define BN     64
#define BK     64
#define NGRP   128   // IN_F / 64
#define KTILES 32    // k-tiles per block (split-K=4)

// Static device scratch — no dependence on d_ws/ws_size.
__device__ unsigned short g_xb[MROWS * IN_F];        // 4 MB bf16 x, fragment-major
__device__ float          g_t[MROWS * 16];           // LoRA intermediate
__device__ float          g_part[4 * MROWS * OUT_F]; // 32 MB split-K partials

// NF4 levels: Phi^{-1}((i+0.5)/16) / Phi^{-1}(15.5/16)
__device__ __constant__ float NF4_LVL[16] = {
  -1.0f,        -0.70756721f, -0.54221982f, -0.41681853f,
  -0.31090474f, -0.21594601f, -0.12734085f, -0.04209530f,
   0.04209530f,  0.12734085f,  0.21594601f,  0.31090474f,
   0.41681853f,  0.54221982f,  0.70756721f,  1.0f };

static __device__ inline uint32_t pkbf(float a, float b) {
  __bf16 ha = (__bf16)a, hb = (__bf16)b;
  return (uint32_t)__builtin_bit_cast(unsigned short, ha)
       | ((uint32_t)__builtin_bit_cast(unsigned short, hb) << 16);
}

// ---- k0: x fp32 -> bf16, fragment-major:
// 16B-chunk d: l15=d&15, sub=(d>>4)&3, kk=(d>>6)&1, m16=(d>>7)&15, kt=d>>11
// holds x[m16*16+l15][kt*64 + (kk*4+sub)*8 .. +8]. Writes perfectly coalesced.
__global__ __launch_bounds__(256) void k_convert(const float* __restrict__ x) {
  int d = blockIdx.x * 256 + threadIdx.x;   // 262144 chunks
  int l15 = d & 15, sub = (d >> 4) & 3, kk = (d >> 6) & 1;
  int m16 = (d >> 7) & 15, kt = d >> 11;
  int r = m16 * 16 + l15;
  int k = kt * 64 + (kk * 4 + sub) * 8;
  const float* src = x + (size_t)r * IN_F + k;
  f32x4 v0 = *(const f32x4*)src;
  f32x4 v1 = *(const f32x4*)(src + 4);
  int4v ov;
  ov[0] = (int)pkbf(v0.x, v0.y); ov[1] = (int)pkbf(v0.z, v0.w);
  ov[2] = (int)pkbf(v1.x, v1.y); ov[3] = (int)pkbf(v1.z, v1.w);
  *(int4v*)(g_xb + (size_t)d * 8) = ov;
}

// ---- k1: g_t = x @ lora_A^T (scaled by 2 at write)
__global__ __launch_bounds__(256) void k_xa(const float* __restrict__ x,
                                            const float* __restrict__ lora_A) {
  int m = blockIdx.x, tid = threadIdx.x;
  float acc[16];
#pragma unroll
  for (int r = 0; r < 16; ++r) acc[r] = 0.f;
  const float* xr = x + (size_t)m * IN_F;
  for (int it = 0; it < 8; ++it) {
    int k = (tid + it * 256) * 4;
    f32x4 xv = *(const f32x4*)(xr + k);
#pragma unroll
    for (int r = 0; r < 16; ++r) {
      f32x4 av = *(const f32x4*)(lora_A + (size_t)r * IN_F + k);
      acc[r] += xv.x * av.x + xv.y * av.y + xv.z * av.z + xv.w * av.w;
    }
  }
#pragma unroll
  for (int r = 0; r < 16; ++r) {
    float v = acc[r];
#pragma unroll
    for (int off = 32; off; off >>= 1) v += __shfl_xor(v, off, 64);
    acc[r] = v;
  }
  __shared__ float sm[4][16];
  int lane = tid & 63, wave = tid >> 6;
  if (lane == 0) {
#pragma unroll
    for (int r = 0; r < 16; ++r) sm[wave][r] = acc[r];
  }
  __syncthreads();
  if (tid < 16)
    g_t[m * 16 + tid] = 2.0f * (sm[0][tid] + sm[1][tid] + sm[2][tid] + sm[3][tid]);
}

// ---- k3: main GEMM. BM=256 x BN=64, BK=64, split-K=4, 512 blocks (2/CU).
// A: direct global->reg fragment loads (L2). B: dequant->LDS dbuf, 1 raw barrier/tile,
// lgkmcnt(0) only (q prefetch flies across barriers).
__global__ __launch_bounds__(512, 4) void k_gemm(
    const int* __restrict__ qw, const float* __restrict__ scales)
{
  __shared__ unsigned short Bl[2][BN * BK];  // 2 x 8 KB
  __shared__ uint32_t lut2[256];             // packed bf16x2: (lv[hi], lv[lo])

  int tid = threadIdx.x;
  int lane = tid & 63, wave = tid >> 6;
  if (tid < 256) lut2[tid] = pkbf(NF4_LVL[tid >> 4], NF4_LVL[tid & 15]);

  // XCD-aware bijective swizzle over 512 blocks
  int flat = blockIdx.x;
  int wg = (flat & 7) * 64 + (flat >> 3);
  int bx = wg & 127, bz = wg >> 7;
  int n0 = bx * BN;
  int ktg0 = bz * KTILES;

  // dequant geometry: thread -> (row dn, 16B chunk dc); 64 rows x 8 chunks
  int dn = tid >> 3, dc = tid & 7;
  const int* qr = qw + (size_t)(n0 + dn) * (IN_F / 2) + dc * 4;
  const float* sr = scales + (size_t)(n0 + dn) * NGRP;
  int boff = dn * 128 + ((dc ^ (dn & 7)) << 4);

  f32x4 acc[4][2];
#pragma unroll
  for (int i = 0; i < 4; ++i)
#pragma unroll
    for (int j = 0; j < 2; ++j) acc[i][j] = (f32x4){0.f, 0.f, 0.f, 0.f};

  int wr = wave >> 1, wc = wave & 1;   // 4 M-groups x 2 N-groups
  int wn = wc * 32;
  int sub = lane >> 4, l15 = lane & 15;

  // A-frag offsets (ushort units): frag(kt, m16, kk) at (kt*16+m16)*1024 + kk*512, lane +(sub*16+l15)*8
  int aoff = (wr * 4) * 1024 + (sub * 16 + l15) * 8;

  auto dqst = [&](int buf, int4v q, float s) {
    int4v ov;
#pragma unroll
    for (int e = 0; e < 4; ++e) {
      uint32_t pk = lut2[q[e] & 255];
      float fh = __builtin_bit_cast(float, pk << 16);
      float fl = __builtin_bit_cast(float, pk & 0xFFFF0000u);
      ov[e] = (int)pkbf(fh * s, fl * s);
    }
    *(int4v*)((char*)(&Bl[buf][0]) + boff) = ov;
  };

  __syncthreads();  // lut ready

  // prologue: stage tile 0, load q[1]
  int4v qcur = *(const int4v*)(qr + ktg0 * 32);
  float scur = sr[ktg0];
  dqst(0, qcur, scur);
  int4v qnxt = *(const int4v*)(qr + (ktg0 + 1) * 32);
  float snxt = sr[ktg0 + 1];
  asm volatile("s_waitcnt lgkmcnt(0)" ::: "memory");
  __builtin_amdgcn_s_barrier();

  for (int t = 0; t < KTILES - 1; ++t) {
    int cur = t & 1;
    int ktg = ktg0 + t;

    // B-frag reads from Bl[cur]
    short8 bfv[2][2];
#pragma unroll
    for (int kk = 0; kk < 2; ++kk)
#pragma unroll
      for (int ni = 0; ni < 2; ++ni) {
        int n = wn + ni * 16 + l15;
        int cch = (kk * 4 + sub) ^ (n & 7);
        bfv[kk][ni] = *(const short8*)((const char*)(&Bl[cur][0]) + n * 128 + cch * 16);
      }

    // A-frag loads (L2-resident fragment-major)
    short8 af[2][4];
    const unsigned short* ab = g_xb + (size_t)ktg * 16384;
#pragma unroll
    for (int kk = 0; kk < 2; ++kk)
#pragma unroll
      for (int mi = 0; mi < 4; ++mi)
        af[kk][mi] = *(const short8*)(ab + aoff + mi * 1024 + kk * 512);

    // q prefetch for tile t+2 (stays in flight across the barrier)
    int kn = (t < KTILES - 2) ? (ktg0 + t + 2) : (ktg0 + KTILES - 1);
    int4v qn2 = *(const int4v*)(qr + kn * 32);
    float sn2 = sr[kn];

    // stage tile t+1 into Bl[cur^1]
    dqst(cur ^ 1, qnxt, snxt);
    qnxt = qn2; snxt = sn2;

    __builtin_amdgcn_s_setprio(1);
#pragma unroll
    for (int kk = 0; kk < 2; ++kk)
#pragma unroll
      for (int mi = 0; mi < 4; ++mi)
#pragma unroll
        for (int ni = 0; ni < 2; ++ni)
          acc[mi][ni] = __builtin_amdgcn_mfma_f32_16x16x32_bf16(
              af[kk][mi], bfv[kk][ni], acc[mi][ni], 0, 0, 0);
    __builtin_amdgcn_s_setprio(0);

    asm volatile("s_waitcnt lgkmcnt(0)" ::: "memory");
    __builtin_amdgcn_s_barrier();
  }

  // final tile (KTILES-1), sits in Bl[(KTILES-1)&1]
  {
    int cur = (KTILES - 1) & 1;
    int ktg = ktg0 + KTILES - 1;
    short8 bfv[2][2];
#pragma unroll
    for (int kk = 0; kk < 2; ++kk)
#pragma unroll
      for (int ni = 0; ni < 2; ++ni) {
        int n = wn + ni * 16 + l15;
        int cch = (kk * 4 + sub) ^ (n & 7);
        bfv[kk][ni] = *(const short8*)((const char*)(&Bl[cur][0]) + n * 128 + cch * 16);
      }
    short8 af[2][4];
    const unsigned short* ab = g_xb + (size_t)ktg * 16384;
#pragma unroll
    for (int kk = 0; kk < 2; ++kk)
#pragma unroll
      for (int mi = 0; mi < 4; ++mi)
        af[kk][mi] = *(const short8*)(ab + aoff + mi * 1024 + kk * 512);
#pragma unroll
    for (int kk = 0; kk < 2; ++kk)
#pragma unroll
      for (int mi = 0; mi < 4; ++mi)
#pragma unroll
        for (int ni = 0; ni < 2; ++ni)
          acc[mi][ni] = __builtin_amdgcn_mfma_f32_16x16x32_bf16(
              af[kk][mi], bfv[kk][ni], acc[mi][ni], 0, 0, 0);
  }

  // epilogue -> per-slice partials. D layout: col=lane&15, row=(lane>>4)*4+reg
  float* op = g_part + (size_t)bz * MROWS * OUT_F;
#pragma unroll
  for (int mi = 0; mi < 4; ++mi) {
#pragma unroll
    for (int ni = 0; ni < 2; ++ni) {
      int m = wr * 64 + mi * 16 + sub * 4;
      int nn = n0 + wn + ni * 16 + l15;
#pragma unroll
      for (int j = 0; j < 4; ++j)
        op[(size_t)(m + j) * OUT_F + nn] = acc[mi][ni][j];
    }
  }
}

// ---- k4: out = sum of 4 split-K partials + LoRA (g_t @ lora_B^T), fused
__global__ __launch_bounds__(256) void k_reduce(const float* __restrict__ lora_B,
                                                float* __restrict__ out) {
  size_t i = ((size_t)blockIdx.x * 256 + threadIdx.x) * 4;
  int m = (int)(i >> 13);
  int n = (int)(i & 8191);
  f32x4 v = *(const f32x4*)(g_part + i);
  v += *(const f32x4*)(g_part + (size_t)1 * MROWS * OUT_F + i);
  v += *(const f32x4*)(g_part + (size_t)2 * MROWS * OUT_F + i);
  v += *(const f32x4*)(g_part + (size_t)3 * MROWS * OUT_F + i);
  const float* tr = g_t + m * 16;
  f32x4 t0 = *(const f32x4*)tr,       t1 = *(const f32x4*)(tr + 4);
  f32x4 t2 = *(const f32x4*)(tr + 8), t3 = *(const f32x4*)(tr + 12);
#pragma unroll
  for (int j = 0; j < 4; ++j) {
    const float* br = lora_B + (size_t)(n + j) * 16;
    f32x4 b0 = *(const f32x4*)br,       b1 = *(const f32x4*)(br + 4);
    f32x4 b2 = *(const f32x4*)(br + 8), b3 = *(const f32x4*)(br + 12);
    v[j] += t0.x*b0.x + t0.y*b0.y + t0.z*b0.z + t0.w*b0.w
          + t1.x*b1.x + t1.y*b1.y + t1.z*b1.z + t1.w*b1.w
          + t2.x*b2.x + t2.y*b2.y + t2.z*b2.z + t2.w*b2.w
          + t3.x*b3.x + t3.y*b3.y + t3.z*b3.z + t3.w*b3.w;
  }
  *(f32x4*)(out + i) = v;
}

extern "C" void kernel_launch(void* const* d_in, const int* in_sizes, int n_in,
                              void* d_out, int out_size, void* d_ws, size_t ws_size,
                              hipStream_t stream) {
  const float* x  = (const float*)d_in[0];
  const int*   qw = (const int*)d_in[1];
  const float* sc = (const float*)d_in[2];
  const float* lA = (const float*)d_in[3];
  const float* lB = (const float*)d_in[4];
  float* out = (float*)d_out;

  k_convert<<<1024, 256, 0, stream>>>(x);
  k_xa<<<256, 256, 0, stream>>>(x, lA);
  k_gemm<<<512, 512, 0, stream>>>(qw, sc);
  k_reduce<<<2048, 256, 0, stream>>>(lB, out);
}

// Round 5
// 105.265 us; speedup vs baseline: 1.0647x; 1.0179x over previous
//
#include <hip/hip_runtime.h>
#include <hip/hip_bf16.h>
#include <stdint.h>

typedef __attribute__((ext_vector_type(4))) float f32x4;
typedef __attribute__((ext_vector_type(8))) short short8;
typedef __attribute__((ext_vector_type(4))) int int4v;

#define IN_F   8192
#define OUT_F  8192
#define MROWS  256
#define BN     64
#define BK     64
#define NGRP   128   // IN_F / 64
#define KTILES 32    // k-tiles per block (split-K=4)

// Static device scratch — no dependence on d_ws/ws_size.
__device__ unsigned short g_xb[MROWS * IN_F];        // 4 MB bf16 x, fragment-major
__device__ float          g_t[MROWS * 16];           // LoRA intermediate
__device__ float          g_part[4 * MROWS * OUT_F]; // 32 MB split-K partials

// NF4 levels: Phi^{-1}((i+0.5)/16) / Phi^{-1}(15.5/16)
__device__ __constant__ float NF4_LVL[16] = {
  -1.0f,        -0.70756721f, -0.54221982f, -0.41681853f,
  -0.31090474f, -0.21594601f, -0.12734085f, -0.04209530f,
   0.04209530f,  0.12734085f,  0.21594601f,  0.31090474f,
   0.41681853f,  0.54221982f,  0.70756721f,  1.0f };

static __device__ inline uint32_t pkbf(float a, float b) {
  __bf16 ha = (__bf16)a, hb = (__bf16)b;
  return (uint32_t)__builtin_bit_cast(unsigned short, ha)
       | ((uint32_t)__builtin_bit_cast(unsigned short, hb) << 16);
}

// ---- k0: x fp32 -> bf16, fragment-major:
// 16B-chunk d: l15=d&15, sub=(d>>4)&3, kk=(d>>6)&1, m16=(d>>7)&15, kt=d>>11
// holds x[m16*16+l15][kt*64 + (kk*4+sub)*8 .. +8]. Writes perfectly coalesced.
__global__ __launch_bounds__(256) void k_convert(const float* __restrict__ x) {
  int d = blockIdx.x * 256 + threadIdx.x;   // 262144 chunks
  int l15 = d & 15, sub = (d >> 4) & 3, kk = (d >> 6) & 1;
  int m16 = (d >> 7) & 15, kt = d >> 11;
  int r = m16 * 16 + l15;
  int k = kt * 64 + (kk * 4 + sub) * 8;
  const float* src = x + (size_t)r * IN_F + k;
  f32x4 v0 = *(const f32x4*)src;
  f32x4 v1 = *(const f32x4*)(src + 4);
  int4v ov;
  ov[0] = (int)pkbf(v0.x, v0.y); ov[1] = (int)pkbf(v0.z, v0.w);
  ov[2] = (int)pkbf(v1.x, v1.y); ov[3] = (int)pkbf(v1.z, v1.w);
  *(int4v*)(g_xb + (size_t)d * 8) = ov;
}

// ---- k1: g_t = 2 * x @ lora_A^T
__global__ __launch_bounds__(256) void k_xa(const float* __restrict__ x,
                                            const float* __restrict__ lora_A) {
  int m = blockIdx.x, tid = threadIdx.x;
  float acc[16];
#pragma unroll
  for (int r = 0; r < 16; ++r) acc[r] = 0.f;
  const float* xr = x + (size_t)m * IN_F;
  for (int it = 0; it < 8; ++it) {
    int k = (tid + it * 256) * 4;
    f32x4 xv = *(const f32x4*)(xr + k);
#pragma unroll
    for (int r = 0; r < 16; ++r) {
      f32x4 av = *(const f32x4*)(lora_A + (size_t)r * IN_F + k);
      acc[r] += xv.x * av.x + xv.y * av.y + xv.z * av.z + xv.w * av.w;
    }
  }
#pragma unroll
  for (int r = 0; r < 16; ++r) {
    float v = acc[r];
#pragma unroll
    for (int off = 32; off; off >>= 1) v += __shfl_xor(v, off, 64);
    acc[r] = v;
  }
  __shared__ float sm[4][16];
  int lane = tid & 63, wave = tid >> 6;
  if (lane == 0) {
#pragma unroll
    for (int r = 0; r < 16; ++r) sm[wave][r] = acc[r];
  }
  __syncthreads();
  if (tid < 16)
    g_t[m * 16 + tid] = 2.0f * (sm[0][tid] + sm[1][tid] + sm[2][tid] + sm[3][tid]);
}

// ---- k3: main GEMM. BM=256 x BN=64, BK=64, split-K=4, 512 blocks (2/CU).
// A: direct global->reg fragment loads (L2). B: dequant->LDS dbuf.
// ONE rolled loop body (I$-resident), one raw barrier per tile, lgkmcnt(0) only.
__global__ __launch_bounds__(512, 4) void k_gemm(
    const int* __restrict__ qw, const float* __restrict__ scales)
{
  __shared__ unsigned short Bl[2][BN * BK];  // 2 x 8 KB
  __shared__ float lut16[16];                // broadcast LUT (0 conflicts measured)

  int tid = threadIdx.x;
  int lane = tid & 63, wave = tid >> 6;
  if (tid < 16) lut16[tid] = NF4_LVL[tid];

  // XCD-aware bijective swizzle over 512 blocks
  int flat = blockIdx.x;
  int wg = (flat & 7) * 64 + (flat >> 3);
  int bx = wg & 127, bz = wg >> 7;
  int n0 = bx * BN;
  int ktg0 = bz * KTILES;

  // dequant geometry: thread -> (row dn, 16B chunk dc); 64 rows x 8 chunks
  int dn = tid >> 3, dc = tid & 7;
  const int* qr = qw + (size_t)(n0 + dn) * (IN_F / 2) + dc * 4;
  const float* sr = scales + (size_t)(n0 + dn) * NGRP;
  int boff = dn * 128 + ((dc ^ (dn & 7)) << 4);

  f32x4 acc[4][2];
#pragma unroll
  for (int i = 0; i < 4; ++i)
#pragma unroll
    for (int j = 0; j < 2; ++j) acc[i][j] = (f32x4){0.f, 0.f, 0.f, 0.f};

  int wr = wave >> 1, wc = wave & 1;   // 4 M-groups x 2 N-groups
  int wn = wc * 32;
  int sub = lane >> 4, l15 = lane & 15;
  int aoff = (wr * 4) * 1024 + (sub * 16 + l15) * 8;

  auto dqst = [&](int buf, int4v q, float s) {
    int4v ov;
#pragma unroll
    for (int e = 0; e < 4; ++e) {
      float hi = lut16[(q[e] >> 4) & 15];
      float lo = lut16[q[e] & 15];
      ov[e] = (int)pkbf(hi * s, lo * s);
    }
    *(int4v*)((char*)(&Bl[buf][0]) + boff) = ov;
  };

  __syncthreads();  // lut ready

  // prologue: stage tile 0 into Bl[0], q[1] into regs
  int4v qcur = *(const int4v*)(qr + ktg0 * 32);
  float scur = sr[ktg0];
  dqst(0, qcur, scur);
  int4v qnxt = *(const int4v*)(qr + (ktg0 + 1) * 32);
  float snxt = sr[ktg0 + 1];
  asm volatile("s_waitcnt lgkmcnt(0)" ::: "memory");
  __builtin_amdgcn_s_barrier();

#pragma clang loop unroll(disable)
  for (int t = 0; t < KTILES; ++t) {
    int cur = t & 1;
    int ktg = ktg0 + t;

    // B frags from Bl[cur]
    short8 bfv[2][2];
#pragma unroll
    for (int kk = 0; kk < 2; ++kk)
#pragma unroll
      for (int ni = 0; ni < 2; ++ni) {
        int n = wn + ni * 16 + l15;
        int cch = (kk * 4 + sub) ^ (n & 7);
        bfv[kk][ni] = *(const short8*)((const char*)(&Bl[cur][0]) + n * 128 + cch * 16);
      }

    // A frags (fragment-major g_xb, L2-resident)
    short8 af[2][4];
    const unsigned short* ab = g_xb + (size_t)ktg * 16384;
#pragma unroll
    for (int kk = 0; kk < 2; ++kk)
#pragma unroll
      for (int mi = 0; mi < 4; ++mi)
        af[kk][mi] = *(const short8*)(ab + aoff + mi * 1024 + kk * 512);

    if (t < KTILES - 1) {
      // q prefetch for t+2 (stays in flight across the barrier)
      int kn = ktg0 + ((t < KTILES - 2) ? (t + 2) : (KTILES - 1));
      int4v qn2 = *(const int4v*)(qr + kn * 32);
      float sn2 = sr[kn];
      // stage tile t+1 into Bl[cur^1]
      dqst(cur ^ 1, qnxt, snxt);
      qnxt = qn2; snxt = sn2;
    }

    __builtin_amdgcn_s_setprio(1);
#pragma unroll
    for (int kk = 0; kk < 2; ++kk)
#pragma unroll
      for (int mi = 0; mi < 4; ++mi)
#pragma unroll
        for (int ni = 0; ni < 2; ++ni)
          acc[mi][ni] = __builtin_amdgcn_mfma_f32_16x16x32_bf16(
              af[kk][mi], bfv[kk][ni], acc[mi][ni], 0, 0, 0);
    __builtin_amdgcn_s_setprio(0);

    if (t < KTILES - 1) {
      asm volatile("s_waitcnt lgkmcnt(0)" ::: "memory");
      __builtin_amdgcn_s_barrier();
    }
  }

  // epilogue -> per-slice partials. D layout: col=lane&15, row=(lane>>4)*4+reg
  float* op = g_part + (size_t)bz * MROWS * OUT_F;
#pragma unroll
  for (int mi = 0; mi < 4; ++mi) {
#pragma unroll
    for (int ni = 0; ni < 2; ++ni) {
      int m = wr * 64 + mi * 16 + sub * 4;
      int nn = n0 + wn + ni * 16 + l15;
#pragma unroll
      for (int j = 0; j < 4; ++j)
        op[(size_t)(m + j) * OUT_F + nn] = acc[mi][ni][j];
    }
  }
}

// ---- k4: out = sum of 4 split-K partials + LoRA (g_t @ lora_B^T), fused
__global__ __launch_bounds__(256) void k_reduce(const float* __restrict__ lora_B,
                                                float* __restrict__ out) {
  size_t i = ((size_t)blockIdx.x * 256 + threadIdx.x) * 4;
  int m = (int)(i >> 13);
  int n = (int)(i & 8191);
  f32x4 v = *(const f32x4*)(g_part + i);
  v += *(const f32x4*)(g_part + (size_t)1 * MROWS * OUT_F + i);
  v += *(const f32x4*)(g_part + (size_t)2 * MROWS * OUT_F + i);
  v += *(const f32x4*)(g_part + (size_t)3 * MROWS * OUT_F + i);
  const float* tr = g_t + m * 16;
  f32x4 t0 = *(const f32x4*)tr,       t1 = *(const f32x4*)(tr + 4);
  f32x4 t2 = *(const f32x4*)(tr + 8), t3 = *(const f32x4*)(tr + 12);
#pragma unroll
  for (int j = 0; j < 4; ++j) {
    const float* br = lora_B + (size_t)(n + j) * 16;
    f32x4 b0 = *(const f32x4*)br,       b1 = *(const f32x4*)(br + 4);
    f32x4 b2 = *(const f32x4*)(br + 8), b3 = *(const f32x4*)(br + 12);
    v[j] += t0.x*b0.x + t0.y*b0.y + t0.z*b0.z + t0.w*b0.w
          + t1.x*b1.x + t1.y*b1.y + t1.z*b1.z + t1.w*b1.w
          + t2.x*b2.x + t2.y*b2.y + t2.z*b2.z + t2.w*b2.w
          + t3.x*b3.x + t3.y*b3.y + t3.z*b3.z + t3.w*b3.w;
  }
  *(f32x4*)(out + i) = v;
}

extern "C" void kernel_launch(void* const* d_in, const int* in_sizes, int n_in,
                              void* d_out, int out_size, void* d_ws, size_t ws_size,
                              hipStream_t stream) {
  const float* x  = (const float*)d_in[0];
  const int*   qw = (const int*)d_in[1];
  const float* sc = (const float*)d_in[2];
  const float* lA = (const float*)d_in[3];
  const float* lB = (const float*)d_in[4];
  float* out = (float*)d_out;

  k_convert<<<1024, 256, 0, stream>>>(x);
  k_xa<<<256, 256, 0, stream>>>(x, lA);
  k_gemm<<<512, 512, 0, stream>>>(qw, sc);
  k_reduce<<<2048, 256, 0, stream>>>(lB, out);
}